// Round 9
// baseline (88.187 us; speedup 1.0000x reference)
//
#include <hip/hip_runtime.h>

// NeRF fused render, R9: interval-scan reformulation.
// relu(A_h + m*B_h) along a ray is active on a sample-interval (prefix or
// suffix of s, since m_s is monotone). Per ray:
//   phase 1: per h, compute crossing sample index; scatter +/-{w_c*A, w_c*B}
//            (8 values) into per-ray difference arrays over s (LDS atomics).
//   phase 2: prefix-scan over s  ->  P_c(s), Q_c(s).
//   phase 3: per sample acc_c = b2_c + P_c + m*Q_c  (4 fma) + composite.
// ~8x fewer FLOPs than the dense 64x per-sample MLP evaluation.

constexpr int S_TOTAL = 128;
constexpr int TPR     = 32;            // lanes per ray
constexpr int SPT     = S_TOTAL / TPR; // 4 samples per lane
constexpr int BLOCK   = 256;
constexpr int RPB     = BLOCK / TPR;   // 8 rays per block
constexpr int H       = 64;
constexpr int SLOTS   = 132;           // 129 used (0..128), padded; 528B stride

__global__ __launch_bounds__(BLOCK, 4)
void nerf_scan(const float* __restrict__ origins,
               const float* __restrict__ directions,
               const float* __restrict__ nearp,
               const float* __restrict__ farp,
               const float* __restrict__ W1,   // [3][64]
               const float* __restrict__ b1,   // [64]
               const float* __restrict__ W2,   // [64][4]
               const float* __restrict__ b2,   // [4]
               float* __restrict__ out,        // [B][3]
               int B)
{
    // channels 0..3: P (constant part) per color/sigma; 4..7: Q (slope part)
    __shared__ float dif[RPB][8][SLOTS];

    const int tid = threadIdx.x;
    {
        float* p = &dif[0][0][0];
        for (int i = tid; i < RPB * 8 * SLOTS; i += BLOCK) p[i] = 0.0f;
    }
    __syncthreads();

    const int rloc = tid >> 5;           // local ray
    const int sub  = tid & 31;           // lane within ray
    const int ray  = blockIdx.x * RPB + rloc;
    const int rayc = (ray < B) ? ray : (B - 1);

    const float nr    = nearp[0];
    const float fr    = farp[0];
    const float delta = (fr - nr) * (1.0f / (float)S_TOTAL);

    const float o0 = origins[rayc * 3 + 0];
    const float o1 = origins[rayc * 3 + 1];
    const float o2 = origins[rayc * 3 + 2];
    float d0 = directions[rayc * 3 + 0];
    float d1 = directions[rayc * 3 + 1];
    float d2 = directions[rayc * 3 + 2];
    const float nrm  = sqrtf(d0 * d0 + d1 * d1 + d2 * d2);
    const float rinv = 1.0f / fmaxf(nrm, 1e-12f);
    d0 *= rinv; d1 *= rinv; d2 *= rinv;

    // ---- phase 1: scatter interval endpoints (2 hidden units per lane) ----
    float* const dp = &dif[rloc][0][0];  // channel stride = SLOTS

#define ATOM8(IDX, SGN)                                                       \
    {                                                                         \
        const int _i = (IDX);                                                 \
        atomicAdd(dp + 0 * SLOTS + _i, SGN wa0);                              \
        atomicAdd(dp + 1 * SLOTS + _i, SGN wa1);                              \
        atomicAdd(dp + 2 * SLOTS + _i, SGN wa2);                              \
        atomicAdd(dp + 3 * SLOTS + _i, SGN wa3);                              \
        atomicAdd(dp + 4 * SLOTS + _i, SGN wb0);                              \
        atomicAdd(dp + 5 * SLOTS + _i, SGN wb1);                              \
        atomicAdd(dp + 6 * SLOTS + _i, SGN wb2);                              \
        atomicAdd(dp + 7 * SLOTS + _i, SGN wb3);                              \
    }

#pragma unroll
    for (int hh = 0; hh < 2; ++hh) {
        const int h = sub + 32 * hh;
        const float u0 = W1[0 * H + h];
        const float u1 = W1[1 * H + h];
        const float u2 = W1[2 * H + h];
        const float A  = fmaf(o2, u2, fmaf(o1, u1, fmaf(o0, u0, b1[h])));
        const float Bc = fmaf(d2, u2, fmaf(d1, u1, d0 * u0));
        // g(s) = C0 + s*slope,  s = sample index, m_s = nr + (s+0.5)*delta
        const float C0    = fmaf(nr + 0.5f * delta, Bc, A);
        const float slope = delta * Bc;

        const float wa0 = W2[h * 4 + 0] * A,  wa1 = W2[h * 4 + 1] * A;
        const float wa2 = W2[h * 4 + 2] * A,  wa3 = W2[h * 4 + 3] * A;
        const float wb0 = W2[h * 4 + 0] * Bc, wb1 = W2[h * 4 + 1] * Bc;
        const float wb2 = W2[h * 4 + 2] * Bc, wb3 = W2[h * 4 + 3] * Bc;

        if (slope > 0.0f) {                       // active = suffix s > sc
            const float sc = -C0 / slope;
            const int lo = (sc < 0.0f) ? 0 : ((int)floorf(sc) + 1);
            if (lo < S_TOTAL) ATOM8(lo, +)
        } else if (slope < 0.0f) {                // active = prefix s < sc
            const float sc = -C0 / slope;
            if (sc > 0.0f) {
                ATOM8(0, +)
                const int hi = (int)ceilf(sc);    // exclusive end
                if (hi < S_TOTAL) ATOM8(hi, -)
            }
        } else {                                  // constant unit
            if (C0 > 0.0f) ATOM8(0, +)
        }
    }
#undef ATOM8
    __syncthreads();

    // ---- phase 2: prefix-scan over s of the 8 channels ----
    const int s0 = sub * SPT;
    float p[8][SPT];
#pragma unroll
    for (int c = 0; c < 8; ++c) {
        const float4 v = *reinterpret_cast<const float4*>(&dif[rloc][c][s0]);
        float v0 = v.x, v1 = v.y, v2 = v.z, v3 = v.w;
        v1 += v0; v2 += v1; v3 += v2;             // lane-local inclusive
        p[c][0] = v0; p[c][1] = v1; p[c][2] = v2; p[c][3] = v3;
    }
#pragma unroll
    for (int c = 0; c < 8; ++c) {
        float t = p[c][3];
#pragma unroll
        for (int off = 1; off < 32; off <<= 1) {
            const float u = __shfl_up(t, off, 32);
            if (sub >= off) t += u;
        }
        float ex = __shfl_up(t, 1, 32);
        ex = (sub == 0) ? 0.0f : ex;
        p[c][0] += ex; p[c][1] += ex; p[c][2] += ex; p[c][3] += ex;
    }

    // ---- phase 3: evaluate + composite (inclusive cumprod) ----
    const float b20 = b2[0], b21 = b2[1], b22 = b2[2], b23 = b2[3];
    float Tloc = 1.0f, orr = 0.0f, og = 0.0f, ob = 0.0f;
#pragma unroll
    for (int k = 0; k < SPT; ++k) {
        const float m  = fmaf((float)(s0 + k) + 0.5f, delta, nr);
        const float c0 = b20 + fmaf(m, p[4][k], p[0][k]);
        const float c1 = b21 + fmaf(m, p[5][k], p[1][k]);
        const float c2 = b22 + fmaf(m, p[6][k], p[2][k]);
        const float sg = b23 + fmaf(m, p[7][k], p[3][k]);
        const float sig = __expf(sg);
        const float e   = __expf(-sig * delta);   // = 1 - alpha
        Tloc *= e;
        const float w = Tloc * (1.0f - e);        // T * alpha (inclusive)
        orr = fmaf(w, __expf(c0), orr);
        og  = fmaf(w, __expf(c1), og);
        ob  = fmaf(w, __expf(c2), ob);
    }

    // ---- stitch across the 32 lanes of this ray ----
    float scan = Tloc;
#pragma unroll
    for (int off = 1; off < 32; off <<= 1) {
        const float v = __shfl_up(scan, off, 32);
        if (sub >= off) scan *= v;
    }
    float pre = __shfl_up(scan, 1, 32);
    if (sub == 0) pre = 1.0f;

    orr *= pre; og *= pre; ob *= pre;
#pragma unroll
    for (int off = 16; off > 0; off >>= 1) {
        orr += __shfl_down(orr, off, 32);
        og  += __shfl_down(og,  off, 32);
        ob  += __shfl_down(ob,  off, 32);
    }

    if (sub == 0 && ray < B) {
        out[ray * 3 + 0] = orr;
        out[ray * 3 + 1] = og;
        out[ray * 3 + 2] = ob;
    }
}

extern "C" void kernel_launch(void* const* d_in, const int* in_sizes, int n_in,
                              void* d_out, int out_size, void* d_ws, size_t ws_size,
                              hipStream_t stream) {
    const float* origins    = (const float*)d_in[0];
    const float* directions = (const float*)d_in[1];
    const float* nearp      = (const float*)d_in[2];
    const float* farp       = (const float*)d_in[3];
    const float* W1         = (const float*)d_in[4];
    const float* b1         = (const float*)d_in[5];
    const float* W2         = (const float*)d_in[6];
    const float* b2         = (const float*)d_in[7];
    float* out              = (float*)d_out;

    const int B    = in_sizes[0] / 3;            // 32768
    const int grid = (B + RPB - 1) / RPB;        // 4096 blocks

    nerf_scan<<<grid, BLOCK, 0, stream>>>(origins, directions, nearp, farp,
                                          W1, b1, W2, b2, out, B);
}